// Round 9
// baseline (322.513 us; speedup 1.0000x reference)
//
#include <hip/hip_runtime.h>
#include <stdint.h>

typedef unsigned long long u64;
typedef float nfloat4 __attribute__((ext_vector_type(4)));  // native vec for nt-store

#define LQ   4096
#define BQ   8
#define KNB  16
#define TPB  512
#define QPB  64                  // queries per block, 8 lanes each
#define BPB  (LQ / QPB)          // 64 blocks per batch

// u32 compare-exchange (full-rate v_min_u32/v_max_u32)
__device__ __forceinline__ void ceu(uint32_t &a, uint32_t &b) {
    const uint32_t mn = a < b ? a : b;
    const uint32_t mx = a < b ? b : a;
    a = mn; b = mx;
}
// f64 compare-exchange (exact 44-bit keys as positive denormals)
__device__ __forceinline__ void ced(double &a, double &b) {
    const double mn = __builtin_fmin(a, b);
    const double mx = __builtin_fmax(a, b);
    a = mn; b = mx;
}
// bit-exact vs reference: no FMA, sum order (x^2+y^2)+z^2  (re-rank only)
__device__ __forceinline__ float dist2(float mx, float my, float mz,
                                       float px, float py, float pz) {
    const float dx = __fsub_rn(mx, px);
    const float dy = __fsub_rn(my, py);
    const float dz = __fsub_rn(mz, pz);
    return __fadd_rn(__fadd_rn(__fmul_rn(dx, dx), __fmul_rn(dy, dy)),
                     __fmul_rn(dz, dz));
}

// Scan key: (f32 dist bits truncated to top 20) << 12 | j — same proven scheme
// as r2-r8 (superset top-32 + exact f64 re-rank).  This round batches 16
// candidates per R-merge: sort-8 x2 (verified Batcher-8) + Batcher odd-even
// merge(8,8) (25 CE), then ONE min-layer + bitonic-merge-16 per 16 cands.
// Min-layer M[i]=min(R[i],K[15-i]) is the 32-elem bitonic half-cleaner — the
// champion's 8-wide merge is the same identity with K padded by +inf.
//
// XCD locality (r8, verified win): b = blockIdx & 7 pins each batch's 64
// blocks to one XCD (64 = 32 CU x 2 blocks), attr stays L2-resident.

__global__ __launch_bounds__(TPB) void knn_fused_kernel(
    const float4* __restrict__ frame4,   // (B, L, 3) float4 view of (B,L,4,3)
    const float4* __restrict__ attr4,    // (B, L, 32) float4 view of (B,L,128)
    float* __restrict__ out_e,           // (B, L, 16, 3)
    nfloat4* __restrict__ outg4)         // (B, L, 16, 32) float4
{
    __shared__ float4 cpos[LQ];                // 64 KB (w = R00, unused in scan)
    __shared__ unsigned short surv[QPB][32];   // 4 KB  per-query top-32 cand idx
    __shared__ int nbrs[QPB][KNB];             // 4 KB  final neighbor idx
    // total 72 KB -> exactly 2 blocks/CU, grid 512 = 2*256: zero tail

    const int b    = blockIdx.x & 7;           // batch -> XCD
    const int qblk = blockIdx.x >> 3;          // 0..63 query chunk
    const int tid  = threadIdx.x;

    const float4* fb = frame4 + (size_t)b * LQ * 3;
    for (int j = tid; j < LQ; j += TPB) cpos[j] = fb[j * 3];
    __syncthreads();   // only barrier: waves are independent afterwards

    const int qloc = tid >> 3;           // 0..63
    const int h    = tid & 7;            // sub-stream within query
    const int l    = qblk * QPB + qloc;
    const float4 me = cpos[l];
    const float mx = me.x, my = me.y, mz = me.z;

    // per-lane running sorted-ascending top-16 of 32-bit keys
    uint32_t R[16];
#pragma unroll
    for (int i = 0; i < 16; ++i) R[i] = 0xFFFFFFFFu;

#pragma unroll 1
    for (int cc = 0; cc < 32; ++cc) {
        uint32_t K[16];
#pragma unroll
        for (int s = 0; s < 16; ++s) {
            const int j = cc * 128 + s * 8 + h;
            const float4 p = cpos[j];            // one ds_read_b128
            const float dx = __fsub_rn(mx, p.x);
            const float dy = __fsub_rn(my, p.y);
            const float dz = __fsub_rn(mz, p.z);
            const float d  = __fmaf_rn(dz, dz, __fmaf_rn(dy, dy, __fmul_rn(dx, dx)));
            K[s] = (__float_as_uint(d) & 0xFFFFF000u) | (unsigned)j;
        }
        // Batcher odd-even mergesort-8 on K[0..7] (19 CE), ascending
        ceu(K[0],K[1]); ceu(K[2],K[3]); ceu(K[4],K[5]); ceu(K[6],K[7]);
        ceu(K[0],K[2]); ceu(K[1],K[3]); ceu(K[4],K[6]); ceu(K[5],K[7]);
        ceu(K[1],K[2]); ceu(K[5],K[6]);
        ceu(K[0],K[4]); ceu(K[1],K[5]); ceu(K[2],K[6]); ceu(K[3],K[7]);
        ceu(K[2],K[4]); ceu(K[3],K[5]);
        ceu(K[1],K[2]); ceu(K[3],K[4]); ceu(K[5],K[6]);
        // Batcher odd-even mergesort-8 on K[8..15] (19 CE), ascending
        ceu(K[8],K[9]);  ceu(K[10],K[11]); ceu(K[12],K[13]); ceu(K[14],K[15]);
        ceu(K[8],K[10]); ceu(K[9],K[11]);  ceu(K[12],K[14]); ceu(K[13],K[15]);
        ceu(K[9],K[10]); ceu(K[13],K[14]);
        ceu(K[8],K[12]); ceu(K[9],K[13]);  ceu(K[10],K[14]); ceu(K[11],K[15]);
        ceu(K[10],K[12]); ceu(K[11],K[13]);
        ceu(K[9],K[10]); ceu(K[11],K[12]); ceu(K[13],K[14]);
        // Batcher odd-even merge(8,8) -> K sorted-16 (25 CE)
        ceu(K[0],K[8]);  ceu(K[1],K[9]);  ceu(K[2],K[10]); ceu(K[3],K[11]);
        ceu(K[4],K[12]); ceu(K[5],K[13]); ceu(K[6],K[14]); ceu(K[7],K[15]);
        ceu(K[4],K[8]);  ceu(K[5],K[9]);  ceu(K[6],K[10]); ceu(K[7],K[11]);
        ceu(K[2],K[4]);  ceu(K[3],K[5]);  ceu(K[6],K[8]);  ceu(K[7],K[9]);
        ceu(K[10],K[12]); ceu(K[11],K[13]);
        ceu(K[1],K[2]);  ceu(K[3],K[4]);  ceu(K[5],K[6]);  ceu(K[7],K[8]);
        ceu(K[9],K[10]); ceu(K[11],K[12]); ceu(K[13],K[14]);
        // min-layer: bottom-16 of (R ∪ K) as a bitonic sequence
#pragma unroll
        for (int i = 0; i < 16; ++i) {
            const uint32_t x = R[i], y = K[15 - i];
            R[i] = x < y ? x : y;
        }
        // bitonic merge-16 -> R sorted ascending
#pragma unroll
        for (int g = 8; g >= 1; g >>= 1)
#pragma unroll
            for (int i = 0; i < 16; ++i)
                if ((i & g) == 0) ceu(R[i], R[i + g]);
    }

    // ---- distributed cross-lane merge over the query's 8 lanes, keeping ALL
    // 128 elements: after this, position p = h*16+i is fully sorted ascending.
    {
        uint32_t P[16];
#pragma unroll
        for (int i = 0; i < 16; ++i) P[i] = __shfl_xor(R[i], 1, 64);
        const bool lo1 = (h & 1) == 0;
#pragma unroll
        for (int i = 0; i < 16; ++i) {
            const uint32_t o = P[15 - i];
            R[i] = lo1 ? (R[i] < o ? R[i] : o) : (R[i] > o ? R[i] : o);
        }
#pragma unroll
        for (int g = 8; g >= 1; g >>= 1)
#pragma unroll
            for (int i = 0; i < 16; ++i)
                if ((i & g) == 0) ceu(R[i], R[i + g]);
    }
    {
        uint32_t P[16];
#pragma unroll
        for (int i = 0; i < 16; ++i) P[i] = __shfl_xor(R[i], 3, 64);
        const bool lo2 = (h & 2) == 0;
#pragma unroll
        for (int i = 0; i < 16; ++i) {
            const uint32_t o = P[15 - i];
            R[i] = lo2 ? (R[i] < o ? R[i] : o) : (R[i] > o ? R[i] : o);
        }
#pragma unroll
        for (int i = 0; i < 16; ++i) P[i] = __shfl_xor(R[i], 1, 64);
        const bool lo1 = (h & 1) == 0;
#pragma unroll
        for (int i = 0; i < 16; ++i) {
            const uint32_t o = P[i];
            R[i] = lo1 ? (R[i] < o ? R[i] : o) : (R[i] > o ? R[i] : o);
        }
#pragma unroll
        for (int g = 8; g >= 1; g >>= 1)
#pragma unroll
            for (int i = 0; i < 16; ++i)
                if ((i & g) == 0) ceu(R[i], R[i + g]);
    }
    {
        uint32_t P[16];
#pragma unroll
        for (int i = 0; i < 16; ++i) P[i] = __shfl_xor(R[i], 7, 64);
        const bool lo4 = (h & 4) == 0;
#pragma unroll
        for (int i = 0; i < 16; ++i) {
            const uint32_t o = P[15 - i];
            R[i] = lo4 ? (R[i] < o ? R[i] : o) : (R[i] > o ? R[i] : o);
        }
#pragma unroll
        for (int i = 0; i < 16; ++i) P[i] = __shfl_xor(R[i], 2, 64);
        const bool lo2 = (h & 2) == 0;
#pragma unroll
        for (int i = 0; i < 16; ++i) {
            const uint32_t o = P[i];
            R[i] = lo2 ? (R[i] < o ? R[i] : o) : (R[i] > o ? R[i] : o);
        }
#pragma unroll
        for (int i = 0; i < 16; ++i) P[i] = __shfl_xor(R[i], 1, 64);
        const bool lo1 = (h & 1) == 0;
#pragma unroll
        for (int i = 0; i < 16; ++i) {
            const uint32_t o = P[i];
            R[i] = lo1 ? (R[i] < o ? R[i] : o) : (R[i] > o ? R[i] : o);
        }
#pragma unroll
        for (int g = 8; g >= 1; g >>= 1)
#pragma unroll
            for (int i = 0; i < 16; ++i)
                if ((i & g) == 0) ceu(R[i], R[i + g]);
    }

    // lanes 0,1 hold the query's top-32 keys -> publish candidate indices
    if (h < 2) {
#pragma unroll
        for (int i = 0; i < 16; ++i)
            surv[qloc][h * 16 + i] = (unsigned short)(R[i] & 0xFFFu);
    }

    // ---- exact re-rank of the 32 survivors with 44-bit keys (f64 denormals).
    // 4 keys per lane; distributed bitonic merge to sorted-32 over 8 lanes.
    double kd[4];
#pragma unroll
    for (int s = 0; s < 4; ++s) {
        const int j = surv[qloc][h * 4 + s];
        const float4 p = cpos[j];
        const float d = dist2(mx, my, mz, p.x, p.y, p.z);
        kd[s] = __builtin_bit_cast(double,
                 ((u64)__float_as_uint(d) << 12) | (unsigned)j);
    }
    ced(kd[0],kd[1]); ced(kd[2],kd[3]); ced(kd[0],kd[2]); ced(kd[1],kd[3]); ced(kd[1],kd[2]);
    {
        double P[4];
#pragma unroll
        for (int s = 0; s < 4; ++s) P[s] = __shfl_xor(kd[s], 1, 64);
        const bool lo1 = (h & 1) == 0;
#pragma unroll
        for (int s = 0; s < 4; ++s) {
            const double o = P[3 - s];
            kd[s] = lo1 ? __builtin_fmin(kd[s], o) : __builtin_fmax(kd[s], o);
        }
        ced(kd[0],kd[2]); ced(kd[1],kd[3]); ced(kd[0],kd[1]); ced(kd[2],kd[3]);
    }
    {
        double P[4];
#pragma unroll
        for (int s = 0; s < 4; ++s) P[s] = __shfl_xor(kd[s], 3, 64);
        const bool lo2 = (h & 2) == 0;
#pragma unroll
        for (int s = 0; s < 4; ++s) {
            const double o = P[3 - s];
            kd[s] = lo2 ? __builtin_fmin(kd[s], o) : __builtin_fmax(kd[s], o);
        }
#pragma unroll
        for (int s = 0; s < 4; ++s) P[s] = __shfl_xor(kd[s], 1, 64);
        const bool lo1 = (h & 1) == 0;
#pragma unroll
        for (int s = 0; s < 4; ++s) {
            const double o = P[s];
            kd[s] = lo1 ? __builtin_fmin(kd[s], o) : __builtin_fmax(kd[s], o);
        }
        ced(kd[0],kd[2]); ced(kd[1],kd[3]); ced(kd[0],kd[1]); ced(kd[2],kd[3]);
    }
    {
        double P[4];
#pragma unroll
        for (int s = 0; s < 4; ++s) P[s] = __shfl_xor(kd[s], 7, 64);
        const bool lo4 = (h & 4) == 0;
#pragma unroll
        for (int s = 0; s < 4; ++s) {
            const double o = P[3 - s];
            kd[s] = lo4 ? __builtin_fmin(kd[s], o) : __builtin_fmax(kd[s], o);
        }
#pragma unroll
        for (int s = 0; s < 4; ++s) P[s] = __shfl_xor(kd[s], 2, 64);
        const bool lo2 = (h & 2) == 0;
#pragma unroll
        for (int s = 0; s < 4; ++s) {
            const double o = P[s];
            kd[s] = lo2 ? __builtin_fmin(kd[s], o) : __builtin_fmax(kd[s], o);
        }
#pragma unroll
        for (int s = 0; s < 4; ++s) P[s] = __shfl_xor(kd[s], 1, 64);
        const bool lo1 = (h & 1) == 0;
#pragma unroll
        for (int s = 0; s < 4; ++s) {
            const double o = P[s];
            kd[s] = lo1 ? __builtin_fmin(kd[s], o) : __builtin_fmax(kd[s], o);
        }
        ced(kd[0],kd[2]); ced(kd[1],kd[3]); ced(kd[0],kd[1]); ced(kd[2],kd[3]);
    }

    // lanes h<4 hold final top-16 (position h*4+s): epilogue
    const size_t gq = (size_t)b * LQ + l;
    if (h < 4) {
        const float4 f1 = fb[l * 3 + 1];
        const float4 f2 = fb[l * 3 + 2];
        const float R00 = me.w, R01 = f1.x, R02 = f1.y;
        const float R10 = f1.z, R11 = f1.w, R12 = f2.x;
        const float R20 = f2.y, R21 = f2.z, R22 = f2.w;
        float e[12];
#pragma unroll
        for (int s = 0; s < 4; ++s) {
            const u64 bits = __builtin_bit_cast(u64, kd[s]);
            const int j = (int)(bits & 0xFFFu);
            nbrs[qloc][h * 4 + s] = j;
            const float4 p = cpos[j];
            const float dx = p.x - mx;        // delta = nbr_center - center
            const float dy = p.y - my;
            const float dz = p.z - mz;
            e[s * 3 + 0] = dx * R00 + dy * R10 + dz * R20;
            e[s * 3 + 1] = dx * R01 + dy * R11 + dz * R21;
            e[s * 3 + 2] = dx * R02 + dy * R12 + dz * R22;
        }
        float4* eo = (float4*)(out_e + gq * 48 + h * 12);
        float4 v0 = {e[0], e[1], e[2],  e[3]};
        float4 v1 = {e[4], e[5], e[6],  e[7]};
        float4 v2 = {e[8], e[9], e[10], e[11]};
        eo[0] = v0; eo[1] = v1; eo[2] = v2;
    }

    // ---- fused gather (per wave: its 8 queries x 16 nbrs x 32 float4) ----
    const float4* ab = attr4 + (((size_t)b) << 12) * 32;
    const int wv = tid >> 6, lane = tid & 63;    // wv = 0..7
    const size_t obase = ((size_t)b * LQ + (size_t)qblk * QPB + (size_t)wv * 8) * 512;
#pragma unroll 8
    for (int it = 0; it < 64; ++it) {
        const int idx = it * 64 + lane;      // 0..4095
        const int qw  = idx >> 9;            // 0..7 within-wave query
        const int r   = idx & 511;
        const int k   = r >> 5, d4 = r & 31;
        const int nb  = nbrs[wv * 8 + qw][k];
        const float4 v = ab[(size_t)nb * 32 + d4];
        nfloat4 nv = {v.x, v.y, v.z, v.w};
        __builtin_nontemporal_store(nv, &outg4[obase + idx]);
    }
}

extern "C" void kernel_launch(void* const* d_in, const int* in_sizes, int n_in,
                              void* d_out, int out_size, void* d_ws, size_t ws_size,
                              hipStream_t stream)
{
    const float* frame = (const float*)d_in[0];   // (8,4096,4,3) f32
    const float* attr  = (const float*)d_in[1];   // (8,4096,128) f32
    float* out = (float*)d_out;                   // euclidian ++ gathered

    nfloat4* outg4 = (nfloat4*)(out + (size_t)BQ * LQ * KNB * 3);
    knn_fused_kernel<<<BQ * BPB, TPB, 0, stream>>>(
        (const float4*)frame, (const float4*)attr, out, outg4);
}